// Round 2
// baseline (283.901 us; speedup 1.0000x reference)
//
#include <hip/hip_runtime.h>
#include <hip/hip_bf16.h>

typedef __bf16 bf16_t;
typedef __bf16 bf16x4 __attribute__((ext_vector_type(4)));
typedef __bf16 bf16x8 __attribute__((ext_vector_type(8)));
typedef float f32x4 __attribute__((ext_vector_type(4)));
typedef unsigned int u32;

#define B_ 4
#define N_ 2048
#define C_ 1024
#define H_ 16
#define D_ 64

#define MFMA32(a, b, c) __builtin_amdgcn_mfma_f32_16x16x32_bf16((a), (b), (c), 0, 0, 0)

#if __has_builtin(__builtin_amdgcn_exp2f)
#define EXP2F(x) __builtin_amdgcn_exp2f(x)
#else
#define EXP2F(x) __expf((x) * 0.6931471805599453f)
#endif

// 0.125 (=1/sqrt(D)) * log2(e): folded into Q at projection time
#define QSCALE 0.18033688011112042f

// async global->LDS, 16B per lane; LDS dst is wave-uniform base + lane*16
__device__ __forceinline__ void async16(const bf16_t* g, bf16_t* l) {
    __builtin_amdgcn_global_load_lds(
        (const u32 __attribute__((address_space(1)))*)g,
        (u32 __attribute__((address_space(3)))*)l, 16, 0, 0);
}

#define SBAR()  asm volatile("s_barrier" ::: "memory")
#define LGKM0() do { asm volatile("s_waitcnt lgkmcnt(0)" ::: "memory"); \
                     __builtin_amdgcn_sched_barrier(0); } while (0)
#define VM4()   asm volatile("s_waitcnt vmcnt(4)" ::: "memory")
#define VM0()   asm volatile("s_waitcnt vmcnt(0)" ::: "memory")

// ---------------------------------------------------------------------------
// x: f32 -> bf16 elementwise, 8 elems/thread
// ---------------------------------------------------------------------------
__global__ __launch_bounds__(256)
void xconv_kernel(const float* __restrict__ x, bf16_t* __restrict__ xb)
{
    const size_t i = ((size_t)blockIdx.x * 256 + threadIdx.x) * 8;
    float4 a = *(const float4*)(x + i);
    float4 b = *(const float4*)(x + i + 4);
    bf16x8 o;
    o[0] = (bf16_t)a.x; o[1] = (bf16_t)a.y; o[2] = (bf16_t)a.z; o[3] = (bf16_t)a.w;
    o[4] = (bf16_t)b.x; o[5] = (bf16_t)b.y; o[6] = (bf16_t)b.z; o[7] = (bf16_t)b.w;
    *(bf16x8*)(xb + i) = o;
}

// ---------------------------------------------------------------------------
// W[K][N] f32 -> Wt[N][K] bf16 (64x64 LDS tile transpose; z picks weight)
// ---------------------------------------------------------------------------
__global__ __launch_bounds__(256)
void wtrans_kernel(const float* __restrict__ W0, const float* __restrict__ W1,
                   const float* __restrict__ W2, const float* __restrict__ W3,
                   bf16_t* __restrict__ T0, bf16_t* __restrict__ T1,
                   bf16_t* __restrict__ T2, bf16_t* __restrict__ T3)
{
    const float* W; bf16_t* T;
    switch (blockIdx.z) {
        case 0:  W = W0; T = T0; break;
        case 1:  W = W1; T = T1; break;
        case 2:  W = W2; T = T2; break;
        default: W = W3; T = T3; break;
    }
    __shared__ bf16_t tile[64 * 72];
    const int tid = threadIdx.x;
    const int r0 = blockIdx.y * 64;          // k block
    const int c0 = blockIdx.x * 64;          // n block

    const int rr = tid >> 4;
    const int cc = (tid & 15) * 4;
    #pragma unroll
    for (int i = 0; i < 4; ++i) {
        const int row = rr + i * 16;
        float4 v = *(const float4*)(W + (size_t)(r0 + row) * C_ + c0 + cc);
        tile[(cc + 0) * 72 + row] = (bf16_t)v.x;
        tile[(cc + 1) * 72 + row] = (bf16_t)v.y;
        tile[(cc + 2) * 72 + row] = (bf16_t)v.z;
        tile[(cc + 3) * 72 + row] = (bf16_t)v.w;
    }
    __syncthreads();
    #pragma unroll
    for (int i = 0; i < 2; ++i) {
        const int ch = i * 256 + tid;
        const int n  = ch >> 3;
        const int k8 = (ch & 7) * 8;
        bf16x8 o = *(const bf16x8*)&tile[n * 72 + k8];
        *(bf16x8*)(T + (size_t)(c0 + n) * C_ + r0 + k8) = o;
    }
}

// ---------------------------------------------------------------------------
// Fused QKV GEMM, 256x256 tile / BK=64 / 8 waves (2Mx4N), 4-phase interleave
// with counted vmcnt. LDS 128KB: [buf][ks][256 rows][32 k] per operand.
// K-slab staged via global_load_lds (linear dest) with pre-swizzled global
// source: position (row, sc) holds k-chunk sc^(row&3) -> conflict-free
// ds_read_b128 fragment reads.
// vmcnt(4) at mid-tile + boundary only (8 loads in flight, wait oldest 4);
// drains to 0 only on the last tile.
// __launch_bounds__(512, 1): round-1 used (512,2) which hipcc took as
// 2 blocks/CU -> 128-VGPR cap -> acc[8][4] (128 f32) SPILLED to scratch
// (VGPR_Count=112, +31MB WRITE / +27MB FETCH). (512,1) caps at 256.
// XCD map: each XCD owns 4 contiguous m-blocks x all 12 n-blocks:
// A-chunk 2MB L2-resident (reused 12x), B 6MB from L3.
// Epilogue: which = n0>>10: 0 -> Qb [B,H,N,D] PRE-SCALED by QSCALE,
// 1 -> Kb [B,H,N,D], 2 -> Vtb [B,H,D,N] (packed 8B stores).
// ---------------------------------------------------------------------------
#define NT_ 16   // K tiles = 1024/64

__device__ __forceinline__ void ld4(const bf16_t* slab, int rbase, int c, int quad,
                                    bf16x8 (&dst)[4])
{
    #pragma unroll
    for (int i = 0; i < 4; ++i) {
        const int row = rbase + i * 16 + c;
        dst[i] = *(const bf16x8*)(slab + row * 32 + ((quad ^ (row & 3)) * 8));
    }
}

__device__ __forceinline__ void mfma16(f32x4 (&acc)[8][4], const bf16x8 (&af)[4],
                                       const bf16x8 (&bfv)[4], int mf0)
{
    #pragma unroll
    for (int i = 0; i < 4; ++i)
        #pragma unroll
        for (int j = 0; j < 4; ++j)
            acc[mf0 + i][j] = MFMA32(af[i], bfv[j], acc[mf0 + i][j]);
}

__device__ __forceinline__ void stage2(const bf16_t* p0, const bf16_t* p1,
                                       bf16_t* slab, int koff, int dstoff)
{
    async16(p0 + koff, slab + dstoff);
    async16(p1 + koff, slab + 4096 + dstoff);
}

__global__ __launch_bounds__(512, 1)
void gemm_qkv_kernel(const bf16_t* __restrict__ A, const bf16_t* __restrict__ Wt,
                     const float* __restrict__ bq, const float* __restrict__ bk,
                     const float* __restrict__ bv,
                     bf16_t* __restrict__ Qb, bf16_t* __restrict__ Kb,
                     bf16_t* __restrict__ Vtb)
{
    __shared__ bf16_t Asm[2][2][256 * 32];   // [buf][ks][row*32 + swz]
    __shared__ bf16_t Bsm[2][2][256 * 32];

    const int tid  = threadIdx.x;            // 0..511
    const int w    = tid >> 6;               // 0..7
    const int lane = tid & 63;
    const int c    = lane & 15;
    const int quad = lane >> 4;
    const int wr   = w >> 2;                 // 0..1 (M)
    const int wc   = w & 3;                  // 0..3 (N)

    // XCD-aware map: grid 384 = 8 XCDs x 48 blocks; XCD x owns m-blocks
    // [4x, 4x+4) x all 12 n-blocks -> A-chunk 2MB stays in x's L2.
    const int bid = blockIdx.x;
    const int x8  = bid & 7;
    const int ii  = bid >> 3;                // 0..47
    const int mb  = x8 * 4 + (ii & 3);       // 0..31
    const int nb  = ii >> 2;                 // 0..11
    const int m0  = mb * 256, n0 = nb * 256;

    // per-thread staging source bases (row/chunk fixed; k advances)
    const int ci0 = tid,       r0s = ci0 >> 2, kc0 = (ci0 & 3) ^ (r0s & 3);
    const int ci1 = tid + 512, r1s = ci1 >> 2, kc1 = (ci1 & 3) ^ (r1s & 3);
    const bf16_t* Ast0 = A  + (size_t)(m0 + r0s) * C_ + kc0 * 8;
    const bf16_t* Ast1 = A  + (size_t)(m0 + r1s) * C_ + kc1 * 8;
    const bf16_t* Bst0 = Wt + (size_t)(n0 + r0s) * C_ + kc0 * 8;
    const bf16_t* Bst1 = Wt + (size_t)(n0 + r1s) * C_ + kc1 * 8;
    const int dstoff = w * 512;              // wave-uniform LDS chunk base (elems)

    f32x4 acc[8][4] = {};
    bf16x8 af[4], bfv[4];

    // prologue: stage tile 0 (order: A-k0, B-k0, A-k1, B-k1)
    stage2(Ast0, Ast1, &Asm[0][0][0], 0,  dstoff);
    stage2(Bst0, Bst1, &Bsm[0][0][0], 0,  dstoff);
    stage2(Ast0, Ast1, &Asm[0][1][0], 32, dstoff);
    stage2(Bst0, Bst1, &Bsm[0][1][0], 32, dstoff);
    VM4();                                   // k0 slabs landed; k1 stay in flight
    SBAR();

    #pragma unroll 2
    for (int t = 0; t < NT_; ++t) {
        const int  cur  = t & 1;
        const bool more = (t + 1) < NT_;
        const int  kn   = (t + 1) << 6;
        const bf16_t* A0 = &Asm[cur][0][0];
        const bf16_t* A1 = &Asm[cur][1][0];
        const bf16_t* B0 = &Bsm[cur][0][0];
        const bf16_t* B1 = &Bsm[cur][1][0];
        bf16_t* nA0 = &Asm[cur ^ 1][0][0];
        bf16_t* nA1 = &Asm[cur ^ 1][1][0];
        bf16_t* nB0 = &Bsm[cur ^ 1][0][0];
        bf16_t* nB1 = &Bsm[cur ^ 1][1][0];

        // ---- P1: ks0, mf 0..3 ----
        ld4(A0, wr * 128,      c, quad, af);
        ld4(B0, wc * 64,       c, quad, bfv);
        if (more) stage2(Ast0, Ast1, nA0, kn, dstoff);
        SBAR();
        LGKM0();
        __builtin_amdgcn_s_setprio(1);
        mfma16(acc, af, bfv, 0);
        __builtin_amdgcn_s_setprio(0);
        SBAR();

        // ---- P2: ks0, mf 4..7 ----
        ld4(A0, wr * 128 + 64, c, quad, af);
        if (more) stage2(Bst0, Bst1, nB0, kn, dstoff);
        SBAR();
        LGKM0();
        __builtin_amdgcn_s_setprio(1);
        mfma16(acc, af, bfv, 4);
        __builtin_amdgcn_s_setprio(0);
        if (more) VM4(); else VM0();         // tile t's k1 slabs landed
        SBAR();

        // ---- P3: ks1, mf 4..7 ----
        ld4(A1, wr * 128 + 64, c, quad, af);
        ld4(B1, wc * 64,       c, quad, bfv);
        if (more) stage2(Ast0, Ast1, nA1, kn + 32, dstoff);
        SBAR();
        LGKM0();
        __builtin_amdgcn_s_setprio(1);
        mfma16(acc, af, bfv, 4);
        __builtin_amdgcn_s_setprio(0);
        SBAR();

        // ---- P4: ks1, mf 0..3 ----
        ld4(A1, wr * 128,      c, quad, af);
        if (more) stage2(Bst0, Bst1, nB1, kn + 32, dstoff);
        SBAR();
        LGKM0();
        __builtin_amdgcn_s_setprio(1);
        mfma16(acc, af, bfv, 0);
        __builtin_amdgcn_s_setprio(0);
        if (more) VM4();                     // next tile's k0 slabs landed
        SBAR();
    }

    const int which = n0 >> 10;              // 0 Q, 1 K, 2 V (tile-uniform)
    const float* bias = (which == 0) ? bq : (which == 1) ? bk : bv;

    #pragma unroll
    for (int nf = 0; nf < 4; ++nf) {
        const int col  = n0 + wc * 64 + nf * 16 + c;
        const int ncol = col & 1023;
        const float bsf = bias[ncol];
        const int h = ncol >> 6, d = ncol & 63;
        #pragma unroll
        for (int mf = 0; mf < 8; ++mf) {
            const int rbase = m0 + wr * 128 + mf * 16 + quad * 4;
            if (which < 2) {
                bf16_t* out = which ? Kb : Qb;
                const float sc = which ? 1.0f : QSCALE;
                #pragma unroll
                for (int r = 0; r < 4; ++r) {
                    const int row = rbase + r;
                    const int bb = row >> 11, n = row & 2047;
                    out[(((size_t)bb * H_ + h) * N_ + n) * D_ + d] =
                        (bf16_t)((acc[mf][nf][r] + bsf) * sc);
                }
            } else {
                const int bb = rbase >> 11, nbv = rbase & 2047;
                bf16x4 o;
                #pragma unroll
                for (int r = 0; r < 4; ++r) o[r] = (bf16_t)(acc[mf][nf][r] + bsf);
                *(bf16x4*)(Vtb + (((size_t)bb * H_ + h) * D_ + d) * N_ + nbv) = o;
            }
        }
    }
}

// ---------------------------------------------------------------------------
// Output GEMM: ctx[8192,1024]bf16 @ Wo_t[1024,1024]^T + bo -> f32 [8192,1024]
// 128x128 tile, BK=64 split-LDS structure (unchanged this round).
// ---------------------------------------------------------------------------
__global__ __launch_bounds__(256)
void gemm_out_kernel(const bf16_t* __restrict__ A, const bf16_t* __restrict__ Bt,
                     const float* __restrict__ bias, float* __restrict__ out)
{
    __shared__ bf16_t As[2][128 * 32];
    __shared__ bf16_t Bs[2][128 * 32];

    const int tid  = threadIdx.x;
    const int w    = tid >> 6;
    const int lane = tid & 63;
    const int c    = lane & 15;
    const int quad = lane >> 4;
    const int n0   = blockIdx.x * 128;
    const int m0   = blockIdx.y * 128;
    const int wm   = (w & 1) * 64;
    const int wn   = (w >> 1) * 64;

    f32x4 acc[4][4] = {};

    for (int k0 = 0; k0 < C_; k0 += 64) {
        __syncthreads();
        #pragma unroll
        for (int hh = 0; hh < 2; ++hh) {
            #pragma unroll
            for (int ph = 0; ph < 2; ++ph) {
                const int ch  = ph * 256 + tid;
                const int row = ch >> 2;
                const int k8  = (ch & 3) * 8;
                const int wbase = (ph * 256 + w * 64) * 8;
                async16(A  + (size_t)(m0 + row) * C_ + k0 + hh * 32 + k8, &As[hh][wbase]);
                async16(Bt + (size_t)(n0 + row) * C_ + k0 + hh * 32 + k8, &Bs[hh][wbase]);
            }
        }
        __syncthreads();

        bf16x8 af[2][4], bfr[2][4];
        #pragma unroll
        for (int hh = 0; hh < 2; ++hh) {
            #pragma unroll
            for (int mf = 0; mf < 4; ++mf)
                af[hh][mf] = *(const bf16x8*)&As[hh][(wm + mf * 16 + c) * 32 + quad * 8];
            #pragma unroll
            for (int nf = 0; nf < 4; ++nf)
                bfr[hh][nf] = *(const bf16x8*)&Bs[hh][(wn + nf * 16 + c) * 32 + quad * 8];
        }

        #pragma unroll
        for (int mf = 0; mf < 4; ++mf)
            #pragma unroll
            for (int nf = 0; nf < 4; ++nf) {
                acc[mf][nf] = MFMA32(af[0][mf], bfr[0][nf], acc[mf][nf]);
                acc[mf][nf] = MFMA32(af[1][mf], bfr[1][nf], acc[mf][nf]);
            }
    }

    #pragma unroll
    for (int nf = 0; nf < 4; ++nf) {
        const int col   = n0 + wn + nf * 16 + c;
        const float bsf = bias[col];
        #pragma unroll
        for (int mf = 0; mf < 4; ++mf) {
            const int rbase = m0 + wm + mf * 16 + quad * 4;
            #pragma unroll
            for (int r = 0; r < 4; ++r)
                out[(size_t)(rbase + r) * C_ + col] = acc[mf][nf][r] + bsf;
        }
    }
}

// ---------------------------------------------------------------------------
// Attention, S^T formulation, no-rescale streaming softmax, prescaled Q.
// Block = 4 waves, 256 q (wave: 64 q = 4 groups of 16 sharing K/V frags).
// Key tiles of 64 staged in LDS (XOR-swizzled 16B chunks).
// launch_bounds(256,2): VGPR est ~185 incl. AGPR accs -- must NOT spill
// (round-6: spills cost ~47MB scratch traffic; watch WRITE_SIZE).
// Grid 512; bh = (bid&7)*8 + ((bid>>3)&7), qtile = bid>>6 (XCD L2 reuse).
// ---------------------------------------------------------------------------
__global__ __launch_bounds__(256, 2)
void attn_kernel(const bf16_t* __restrict__ Q, const bf16_t* __restrict__ K,
                 const bf16_t* __restrict__ Vt, bf16_t* __restrict__ ctx)
{
    __shared__ bf16_t ksh[64 * 64];
    __shared__ bf16_t vsh[64 * 64];

    const int tid  = threadIdx.x;
    const int w    = tid >> 6;
    const int lane = tid & 63;
    const int c    = lane & 15;
    const int quad = lane >> 4;

    const int bid   = blockIdx.x;
    const int bh    = (bid & 7) * 8 + ((bid >> 3) & 7);   // 0..63
    const int qtile = bid >> 6;                           // 0..7
    const int b = bh >> 4, h = bh & 15;
    const size_t base = (size_t)bh * N_ * D_;
    const int qb = qtile * 256 + w * 64;                  // wave's 64 q-rows

    bf16x8 qf[4][2];
    #pragma unroll
    for (int g = 0; g < 4; ++g)
        #pragma unroll
        for (int hh = 0; hh < 2; ++hh)
            qf[g][hh] = *(const bf16x8*)(Q + base + (size_t)(qb + g * 16 + c) * D_ + hh * 32 + quad * 8);

    bf16x8 ones;
    #pragma unroll
    for (int j = 0; j < 8; ++j) ones[j] = (bf16_t)1.0f;

    f32x4 O[4][4] = {};
    f32x4 O5[4] = {};                               // row-sum accumulators

    for (int kt = 0; kt < N_; kt += 64) {
        __syncthreads();
        #pragma unroll
        for (int ph = 0; ph < 2; ++ph) {
            const int ch = ph * 256 + tid;       // 0..511
            const int rr = ch >> 3;              // key (K) / d (V)
            const int e8 = ch & 7;
            const int sw = (e8 ^ (rr & 7)) * 8;
            bf16x8 kv = *(const bf16x8*)(K  + base + (size_t)(kt + rr) * D_ + e8 * 8);
            *(bf16x8*)&ksh[rr * 64 + sw] = kv;
            bf16x8 vv = *(const bf16x8*)(Vt + base + (size_t)rr * N_ + kt + e8 * 8);
            *(bf16x8*)&vsh[rr * 64 + sw] = vv;
        }
        __syncthreads();

        #pragma unroll
        for (int ss = 0; ss < 2; ++ss) {         // two 32-key sub-steps
            bf16x8 kb[2][2];
            #pragma unroll
            for (int s2 = 0; s2 < 2; ++s2) {
                const int key = (ss * 2 + s2) * 16 + c;
                #pragma unroll
                for (int hh = 0; hh < 2; ++hh)
                    kb[s2][hh] = *(const bf16x8*)&ksh[key * 64 + (((hh * 4 + quad) ^ (c & 7)) * 8)];
            }
            bf16x8 va[4];
            const int k8lo = ss * 4 + (quad >> 1);
            const int half = (quad & 1) * 4;
            #pragma unroll
            for (int df = 0; df < 4; ++df) {
                const int row = (df * 16 + c) * 64;
                bf16x4 lo = *(const bf16x4*)&vsh[row + ((k8lo       ^ (c & 7)) * 8) + half];
                bf16x4 hi = *(const bf16x4*)&vsh[row + (((k8lo + 2) ^ (c & 7)) * 8) + half];
                #pragma unroll
                for (int j = 0; j < 4; ++j) { va[df][j] = lo[j]; va[df][4 + j] = hi[j]; }
            }

            #pragma unroll
            for (int g = 0; g < 4; ++g) {
                f32x4 s0 = {}, s1 = {};
                s0 = MFMA32(kb[0][0], qf[g][0], s0);
                s0 = MFMA32(kb[0][1], qf[g][1], s0);
                s1 = MFMA32(kb[1][0], qf[g][0], s1);
                s1 = MFMA32(kb[1][1], qf[g][1], s1);

                bf16x8 pb;
                #pragma unroll
                for (int r = 0; r < 4; ++r) {
                    pb[r]     = (bf16_t)EXP2F(s0[r]);
                    pb[4 + r] = (bf16_t)EXP2F(s1[r]);
                }

                #pragma unroll
                for (int df = 0; df < 4; ++df)
                    O[g][df] = MFMA32(va[df], pb, O[g][df]);
                O5[g] = MFMA32(ones, pb, O5[g]);   // l accumulation
            }
        }
    }

    #pragma unroll
    for (int g = 0; g < 4; ++g) {
        const float inv_l = 1.0f / O5[g][0];       // full row-sum for q
        const int q = qb + g * 16 + c;
        #pragma unroll
        for (int df = 0; df < 4; ++df) {
            bf16x4 o;
            #pragma unroll
            for (int r = 0; r < 4; ++r) o[r] = (bf16_t)(O[g][df][r] * inv_l);
            *(bf16x4*)(ctx + ((size_t)b * N_ + q) * C_ + h * 64 + df * 16 + quad * 4) = o;
        }
    }
}

extern "C" void kernel_launch(void* const* d_in, const int* in_sizes, int n_in,
                              void* d_out, int out_size, void* d_ws, size_t ws_size,
                              hipStream_t stream) {
    const float* x  = (const float*)d_in[0];
    const float* Wq = (const float*)d_in[1];
    const float* bq = (const float*)d_in[2];
    const float* Wk = (const float*)d_in[3];
    const float* bk = (const float*)d_in[4];
    const float* Wv = (const float*)d_in[5];
    const float* bv = (const float*)d_in[6];
    const float* Wo = (const float*)d_in[7];
    const float* bo = (const float*)d_in[8];

    bf16_t* ws = (bf16_t*)d_ws;
    const size_t per = (size_t)B_ * N_ * C_;     // 8,388,608 elems
    bf16_t* xb  = ws;                            // reused as ctx after QKV
    bf16_t* ctx = ws;
    bf16_t* Qb  = ws + per;
    bf16_t* Kb  = ws + 2 * per;
    bf16_t* Vtb = ws + 3 * per;
    bf16_t* Wtqkv = ws + 4 * per;                // [3072][1024] concatenated
    bf16_t* Wtq = Wtqkv;
    bf16_t* Wtk = Wtqkv + (size_t)C_ * C_;
    bf16_t* Wtv = Wtqkv + 2 * (size_t)C_ * C_;
    bf16_t* Wto = Wtqkv + 3 * (size_t)C_ * C_;

    dim3 blk(256);

    xconv_kernel<<<dim3(per / 2048), blk, 0, stream>>>(x, xb);
    wtrans_kernel<<<dim3(16, 16, 4), blk, 0, stream>>>(Wq, Wk, Wv, Wo, Wtq, Wtk, Wtv, Wto);

    gemm_qkv_kernel<<<dim3(384), dim3(512), 0, stream>>>(xb, Wtqkv, bq, bk, bv, Qb, Kb, Vtb);

    attn_kernel<<<dim3(512), blk, 0, stream>>>(Qb, Kb, Vtb, ctx);

    gemm_out_kernel<<<dim3(8, 64), blk, 0, stream>>>(ctx, Wto, bo, (float*)d_out);
}

// Round 3
// 273.920 us; speedup vs baseline: 1.0364x; 1.0364x over previous
//
#include <hip/hip_runtime.h>
#include <hip/hip_bf16.h>

typedef __bf16 bf16_t;
typedef __bf16 bf16x4 __attribute__((ext_vector_type(4)));
typedef __bf16 bf16x8 __attribute__((ext_vector_type(8)));
typedef float f32x4 __attribute__((ext_vector_type(4)));
typedef unsigned int u32;

#define B_ 4
#define N_ 2048
#define C_ 1024
#define H_ 16
#define D_ 64

#define MFMA32(a, b, c) __builtin_amdgcn_mfma_f32_16x16x32_bf16((a), (b), (c), 0, 0, 0)

#if __has_builtin(__builtin_amdgcn_exp2f)
#define EXP2F(x) __builtin_amdgcn_exp2f(x)
#else
#define EXP2F(x) __expf((x) * 0.6931471805599453f)
#endif

// 0.125 (=1/sqrt(D)) * log2(e): folded into Q at projection time
#define QSCALE 0.18033688011112042f

// async global->LDS, 16B per lane; LDS dst is wave-uniform base + lane*16
__device__ __forceinline__ void async16(const bf16_t* g, bf16_t* l) {
    __builtin_amdgcn_global_load_lds(
        (const u32 __attribute__((address_space(1)))*)g,
        (u32 __attribute__((address_space(3)))*)l, 16, 0, 0);
}

#define SBAR()  asm volatile("s_barrier" ::: "memory")
#define VM4()   asm volatile("s_waitcnt vmcnt(4)" ::: "memory")
#define VM0()   asm volatile("s_waitcnt vmcnt(0)" ::: "memory")

// ---------------------------------------------------------------------------
// x: f32 -> bf16 elementwise, 8 elems/thread
// ---------------------------------------------------------------------------
__global__ __launch_bounds__(256)
void xconv_kernel(const float* __restrict__ x, bf16_t* __restrict__ xb)
{
    const size_t i = ((size_t)blockIdx.x * 256 + threadIdx.x) * 8;
    float4 a = *(const float4*)(x + i);
    float4 b = *(const float4*)(x + i + 4);
    bf16x8 o;
    o[0] = (bf16_t)a.x; o[1] = (bf16_t)a.y; o[2] = (bf16_t)a.z; o[3] = (bf16_t)a.w;
    o[4] = (bf16_t)b.x; o[5] = (bf16_t)b.y; o[6] = (bf16_t)b.z; o[7] = (bf16_t)b.w;
    *(bf16x8*)(xb + i) = o;
}

// ---------------------------------------------------------------------------
// W[K][N] f32 -> Wt[N][K] bf16 (64x64 LDS tile transpose; z picks weight)
// ---------------------------------------------------------------------------
__global__ __launch_bounds__(256)
void wtrans_kernel(const float* __restrict__ W0, const float* __restrict__ W1,
                   const float* __restrict__ W2, const float* __restrict__ W3,
                   bf16_t* __restrict__ T0, bf16_t* __restrict__ T1,
                   bf16_t* __restrict__ T2, bf16_t* __restrict__ T3)
{
    const float* W; bf16_t* T;
    switch (blockIdx.z) {
        case 0:  W = W0; T = T0; break;
        case 1:  W = W1; T = T1; break;
        case 2:  W = W2; T = T2; break;
        default: W = W3; T = T3; break;
    }
    __shared__ bf16_t tile[64 * 72];
    const int tid = threadIdx.x;
    const int r0 = blockIdx.y * 64;          // k block
    const int c0 = blockIdx.x * 64;          // n block

    const int rr = tid >> 4;
    const int cc = (tid & 15) * 4;
    #pragma unroll
    for (int i = 0; i < 4; ++i) {
        const int row = rr + i * 16;
        float4 v = *(const float4*)(W + (size_t)(r0 + row) * C_ + c0 + cc);
        tile[(cc + 0) * 72 + row] = (bf16_t)v.x;
        tile[(cc + 1) * 72 + row] = (bf16_t)v.y;
        tile[(cc + 2) * 72 + row] = (bf16_t)v.z;
        tile[(cc + 3) * 72 + row] = (bf16_t)v.w;
    }
    __syncthreads();
    #pragma unroll
    for (int i = 0; i < 2; ++i) {
        const int ch = i * 256 + tid;
        const int n  = ch >> 3;
        const int k8 = (ch & 7) * 8;
        bf16x8 o = *(const bf16x8*)&tile[n * 72 + k8];
        *(bf16x8*)(T + (size_t)(c0 + n) * C_ + r0 + k8) = o;
    }
}

// ---------------------------------------------------------------------------
// Fused QKV GEMM, 256x256 tile / BK=64 / 8 waves (2Mx4N), 4-phase interleave
// with counted vmcnt. LDS 128KB flat: smem[op:2][buf:2][ks:2][256*32].
// Staged via global_load_lds (linear dest) with pre-swizzled global source:
// LDS (row, chunk sc) holds global k-chunk sc^(row&3) -> conflict-free
// ds_read_b128 (read chunk quad at LDS chunk quad^(c&3); row&3==c&3 since
// all row-block offsets are multiples of 64).
// All LDS reads = ONE per-thread base per operand + compile-time offsets
// (<=56KB, fits 16-bit ds offset imm). Buf indices are literals (explicit
// two-tile unroll) -- no runtime-cur pointers.
// vmcnt(4) at mid-tile + boundary only; drains to 0 only at the last tile.
// amdgpu_waves_per_eu(2,2): rounds 1-2 spilled ~240B/thread to scratch
// (VGPR_Count=112, WRITE_SIZE 96MB vs 50 ideal) because launch_bounds only
// sets a MIN -- allocator targeted higher occupancy than the 128KB-LDS cap
// (1 block/CU = 2 waves/SIMD) and capped regs below the 128-f32 acc. Pinning
// waves/EU to exactly 2 gives the full 256-reg budget.
// Epilogue: which = n0>>10: 0 -> Qb [B,H,N,D] PRE-SCALED by QSCALE,
// 1 -> Kb [B,H,N,D], 2 -> Vtb [B,H,D,N] (packed 8B stores).
// ---------------------------------------------------------------------------

__device__ __forceinline__ void mfma16(f32x4 (&acc)[8][4], const bf16x8 (&af)[4],
                                       const bf16x8 (&bfv)[4], int mf0)
{
    #pragma unroll
    for (int i = 0; i < 4; ++i)
        #pragma unroll
        for (int j = 0; j < 4; ++j)
            acc[mf0 + i][j] = MFMA32(af[i], bfv[j], acc[mf0 + i][j]);
}

__global__ __launch_bounds__(512) __attribute__((amdgpu_waves_per_eu(2, 2)))
void gemm_qkv_kernel(const bf16_t* __restrict__ A, const bf16_t* __restrict__ Wt,
                     const float* __restrict__ bq, const float* __restrict__ bk,
                     const float* __restrict__ bv,
                     bf16_t* __restrict__ Qb, bf16_t* __restrict__ Kb,
                     bf16_t* __restrict__ Vtb)
{
    __shared__ bf16_t smem[65536];           // 128 KiB: [op][buf][ks][8192]

    const int tid  = threadIdx.x;            // 0..511
    const int w    = tid >> 6;               // 0..7
    const int lane = tid & 63;
    const int c    = lane & 15;
    const int quad = lane >> 4;
    const int wr   = w >> 2;                 // 0..1 (M)
    const int wc   = w & 3;                  // 0..3 (N)

    // XCD-aware map: grid 384 = 8 XCDs x 48 blocks; XCD x owns m-blocks
    // [4x, 4x+4) x all 12 n-blocks -> A-chunk 2MB stays in x's L2.
    const int bid = blockIdx.x;
    const int x8  = bid & 7;
    const int ii  = bid >> 3;                // 0..47
    const int mb  = x8 * 4 + (ii & 3);       // 0..31
    const int nb  = ii >> 2;                 // 0..11
    const int m0  = mb * 256, n0 = nb * 256;

    // staging: thread -> (row tid>>2 and +128, chunk tid&3), source k-chunk
    // pre-swizzled: kc = (tid&3) ^ (row&3); rows 128 apart share kc.
    const int r0s = tid >> 2;
    const int kc  = (tid & 3) ^ (r0s & 3);
    const bf16_t* Ast0 = A  + (size_t)(m0 + r0s) * C_ + kc * 8;
    const bf16_t* Ast1 = A  + (size_t)(m0 + r0s + 128) * C_ + kc * 8;
    const bf16_t* Bst0 = Wt + (size_t)(n0 + r0s) * C_ + kc * 8;
    const bf16_t* Bst1 = Wt + (size_t)(n0 + r0s + 128) * C_ + kc * 8;

    // LDS bases: reads (per-thread) and staging dst (wave-uniform)
    const int xorc = (quad ^ (c & 3)) * 8;
    const bf16_t* Ard = smem + (wr * 128 + c) * 32 + xorc;
    const bf16_t* Brd = smem + 32768 + (wc * 64 + c) * 32 + xorc;
    bf16_t* sAB = smem + w * 512;

#define STAGE_A(BUF, KS, KOFF) do { \
    async16(Ast0 + (KOFF), sAB + (BUF) * 16384 + (KS) * 8192); \
    async16(Ast1 + (KOFF), sAB + (BUF) * 16384 + (KS) * 8192 + 4096); } while (0)
#define STAGE_B(BUF, KS, KOFF) do { \
    async16(Bst0 + (KOFF), sAB + 32768 + (BUF) * 16384 + (KS) * 8192); \
    async16(Bst1 + (KOFF), sAB + 32768 + (BUF) * 16384 + (KS) * 8192 + 4096); } while (0)
#define LD4A(BUF, KS, HALF) do { \
    af[0] = *(const bf16x8*)(Ard + (BUF) * 16384 + (KS) * 8192 + (HALF) * 2048); \
    af[1] = *(const bf16x8*)(Ard + (BUF) * 16384 + (KS) * 8192 + (HALF) * 2048 + 512); \
    af[2] = *(const bf16x8*)(Ard + (BUF) * 16384 + (KS) * 8192 + (HALF) * 2048 + 1024); \
    af[3] = *(const bf16x8*)(Ard + (BUF) * 16384 + (KS) * 8192 + (HALF) * 2048 + 1536); } while (0)
#define LD4B(BUF, KS) do { \
    bfv[0] = *(const bf16x8*)(Brd + (BUF) * 16384 + (KS) * 8192); \
    bfv[1] = *(const bf16x8*)(Brd + (BUF) * 16384 + (KS) * 8192 + 512); \
    bfv[2] = *(const bf16x8*)(Brd + (BUF) * 16384 + (KS) * 8192 + 1024); \
    bfv[3] = *(const bf16x8*)(Brd + (BUF) * 16384 + (KS) * 8192 + 1536); } while (0)

// One 64-K tile on buffer CUR. 4 phases: (ks0,lo)(ks0,hi)(ks1,hi)(ks1,lo);
// bfv loaded once per ks, af twice. Stages next tile into buf CUR^1 at
// pointer offsets +64/+96; pointers advance +64 at tile end.
#define TILE(CUR, DOSTAGE) do { \
    LD4A(CUR, 0, 0); LD4B(CUR, 0); \
    if (DOSTAGE) STAGE_A(1 - (CUR), 0, 64); \
    SBAR(); \
    __builtin_amdgcn_s_setprio(1); mfma16(acc, af, bfv, 0); __builtin_amdgcn_s_setprio(0); \
    SBAR(); \
    LD4A(CUR, 0, 1); \
    if (DOSTAGE) STAGE_B(1 - (CUR), 0, 64); \
    SBAR(); \
    __builtin_amdgcn_s_setprio(1); mfma16(acc, af, bfv, 4); __builtin_amdgcn_s_setprio(0); \
    if (DOSTAGE) VM4(); else VM0(); \
    SBAR(); \
    LD4A(CUR, 1, 1); LD4B(CUR, 1); \
    if (DOSTAGE) STAGE_A(1 - (CUR), 1, 96); \
    SBAR(); \
    __builtin_amdgcn_s_setprio(1); mfma16(acc, af, bfv, 4); __builtin_amdgcn_s_setprio(0); \
    SBAR(); \
    LD4A(CUR, 1, 0); \
    if (DOSTAGE) STAGE_B(1 - (CUR), 1, 96); \
    SBAR(); \
    __builtin_amdgcn_s_setprio(1); mfma16(acc, af, bfv, 0); __builtin_amdgcn_s_setprio(0); \
    if (DOSTAGE) { VM4(); Ast0 += 64; Ast1 += 64; Bst0 += 64; Bst1 += 64; } \
    SBAR(); \
} while (0)

    f32x4 acc[8][4] = {};
    bf16x8 af[4], bfv[4];

    // prologue: stage tile 0 (A-k0, B-k0, A-k1, B-k1); wait k0 pair only
    STAGE_A(0, 0, 0);
    STAGE_B(0, 0, 0);
    STAGE_A(0, 1, 32);
    STAGE_B(0, 1, 32);
    VM4();
    SBAR();

    #pragma unroll 1
    for (int tt = 0; tt < 7; ++tt) {         // tiles 0..13
        TILE(0, 1);
        TILE(1, 1);
    }
    TILE(0, 1);                              // tile 14, stages tile 15
    TILE(1, 0);                              // tile 15, drain

#undef TILE
#undef LD4A
#undef LD4B
#undef STAGE_A
#undef STAGE_B

    const int which = n0 >> 10;              // 0 Q, 1 K, 2 V (tile-uniform)
    const float* bias = (which == 0) ? bq : (which == 1) ? bk : bv;

    #pragma unroll
    for (int nf = 0; nf < 4; ++nf) {
        const int col  = n0 + wc * 64 + nf * 16 + c;
        const int ncol = col & 1023;
        const float bsf = bias[ncol];
        const int h = ncol >> 6, d = ncol & 63;
        #pragma unroll
        for (int mf = 0; mf < 8; ++mf) {
            const int rbase = m0 + wr * 128 + mf * 16 + quad * 4;
            if (which < 2) {
                bf16_t* out = which ? Kb : Qb;
                const float sc = which ? 1.0f : QSCALE;
                #pragma unroll
                for (int r = 0; r < 4; ++r) {
                    const int row = rbase + r;
                    const int bb = row >> 11, n = row & 2047;
                    out[(((size_t)bb * H_ + h) * N_ + n) * D_ + d] =
                        (bf16_t)((acc[mf][nf][r] + bsf) * sc);
                }
            } else {
                const int bb = rbase >> 11, nbv = rbase & 2047;
                bf16x4 o;
                #pragma unroll
                for (int r = 0; r < 4; ++r) o[r] = (bf16_t)(acc[mf][nf][r] + bsf);
                *(bf16x4*)(Vtb + (((size_t)bb * H_ + h) * D_ + d) * N_ + nbv) = o;
            }
        }
    }
}

// ---------------------------------------------------------------------------
// Output GEMM: ctx[8192,1024]bf16 @ Wo_t[1024,1024]^T + bo -> f32 [8192,1024]
// 128x128 tile, BK=64 split-LDS structure (unchanged this round).
// ---------------------------------------------------------------------------
__global__ __launch_bounds__(256)
void gemm_out_kernel(const bf16_t* __restrict__ A, const bf16_t* __restrict__ Bt,
                     const float* __restrict__ bias, float* __restrict__ out)
{
    __shared__ bf16_t As[2][128 * 32];
    __shared__ bf16_t Bs[2][128 * 32];

    const int tid  = threadIdx.x;
    const int w    = tid >> 6;
    const int lane = tid & 63;
    const int c    = lane & 15;
    const int quad = lane >> 4;
    const int n0   = blockIdx.x * 128;
    const int m0   = blockIdx.y * 128;
    const int wm   = (w & 1) * 64;
    const int wn   = (w >> 1) * 64;

    f32x4 acc[4][4] = {};

    for (int k0 = 0; k0 < C_; k0 += 64) {
        __syncthreads();
        #pragma unroll
        for (int hh = 0; hh < 2; ++hh) {
            #pragma unroll
            for (int ph = 0; ph < 2; ++ph) {
                const int ch  = ph * 256 + tid;
                const int row = ch >> 2;
                const int k8  = (ch & 3) * 8;
                const int wbase = (ph * 256 + w * 64) * 8;
                async16(A  + (size_t)(m0 + row) * C_ + k0 + hh * 32 + k8, &As[hh][wbase]);
                async16(Bt + (size_t)(n0 + row) * C_ + k0 + hh * 32 + k8, &Bs[hh][wbase]);
            }
        }
        __syncthreads();

        bf16x8 af[2][4], bfr[2][4];
        #pragma unroll
        for (int hh = 0; hh < 2; ++hh) {
            #pragma unroll
            for (int mf = 0; mf < 4; ++mf)
                af[hh][mf] = *(const bf16x8*)&As[hh][(wm + mf * 16 + c) * 32 + quad * 8];
            #pragma unroll
            for (int nf = 0; nf < 4; ++nf)
                bfr[hh][nf] = *(const bf16x8*)&Bs[hh][(wn + nf * 16 + c) * 32 + quad * 8];
        }

        #pragma unroll
        for (int mf = 0; mf < 4; ++mf)
            #pragma unroll
            for (int nf = 0; nf < 4; ++nf) {
                acc[mf][nf] = MFMA32(af[0][mf], bfr[0][nf], acc[mf][nf]);
                acc[mf][nf] = MFMA32(af[1][mf], bfr[1][nf], acc[mf][nf]);
            }
    }

    #pragma unroll
    for (int nf = 0; nf < 4; ++nf) {
        const int col   = n0 + wn + nf * 16 + c;
        const float bsf = bias[col];
        #pragma unroll
        for (int mf = 0; mf < 4; ++mf) {
            const int rbase = m0 + wm + mf * 16 + quad * 4;
            #pragma unroll
            for (int r = 0; r < 4; ++r)
                out[(size_t)(rbase + r) * C_ + col] = acc[mf][nf][r] + bsf;
        }
    }
}

// ---------------------------------------------------------------------------
// Attention, S^T formulation, no-rescale streaming softmax, prescaled Q.
// Block = 4 waves, 256 q (wave: 64 q = 4 groups of 16 sharing K/V frags).
// Key tiles of 64 staged in LDS (XOR-swizzled 16B chunks).
// launch_bounds(256,2): VGPR est ~185 incl. AGPR accs -- must NOT spill
// (round-6: spills cost ~47MB scratch traffic; watch WRITE_SIZE).
// Grid 512; bh = (bid&7)*8 + ((bid>>3)&7), qtile = bid>>6 (XCD L2 reuse).
// ---------------------------------------------------------------------------
__global__ __launch_bounds__(256, 2)
void attn_kernel(const bf16_t* __restrict__ Q, const bf16_t* __restrict__ K,
                 const bf16_t* __restrict__ Vt, bf16_t* __restrict__ ctx)
{
    __shared__ bf16_t ksh[64 * 64];
    __shared__ bf16_t vsh[64 * 64];

    const int tid  = threadIdx.x;
    const int w    = tid >> 6;
    const int lane = tid & 63;
    const int c    = lane & 15;
    const int quad = lane >> 4;

    const int bid   = blockIdx.x;
    const int bh    = (bid & 7) * 8 + ((bid >> 3) & 7);   // 0..63
    const int qtile = bid >> 6;                           // 0..7
    const int b = bh >> 4, h = bh & 15;
    const size_t base = (size_t)bh * N_ * D_;
    const int qb = qtile * 256 + w * 64;                  // wave's 64 q-rows

    bf16x8 qf[4][2];
    #pragma unroll
    for (int g = 0; g < 4; ++g)
        #pragma unroll
        for (int hh = 0; hh < 2; ++hh)
            qf[g][hh] = *(const bf16x8*)(Q + base + (size_t)(qb + g * 16 + c) * D_ + hh * 32 + quad * 8);

    bf16x8 ones;
    #pragma unroll
    for (int j = 0; j < 8; ++j) ones[j] = (bf16_t)1.0f;

    f32x4 O[4][4] = {};
    f32x4 O5[4] = {};                               // row-sum accumulators

    for (int kt = 0; kt < N_; kt += 64) {
        __syncthreads();
        #pragma unroll
        for (int ph = 0; ph < 2; ++ph) {
            const int ch = ph * 256 + tid;       // 0..511
            const int rr = ch >> 3;              // key (K) / d (V)
            const int e8 = ch & 7;
            const int sw = (e8 ^ (rr & 7)) * 8;
            bf16x8 kv = *(const bf16x8*)(K  + base + (size_t)(kt + rr) * D_ + e8 * 8);
            *(bf16x8*)&ksh[rr * 64 + sw] = kv;
            bf16x8 vv = *(const bf16x8*)(Vt + base + (size_t)rr * N_ + kt + e8 * 8);
            *(bf16x8*)&vsh[rr * 64 + sw] = vv;
        }
        __syncthreads();

        #pragma unroll
        for (int ss = 0; ss < 2; ++ss) {         // two 32-key sub-steps
            bf16x8 kb[2][2];
            #pragma unroll
            for (int s2 = 0; s2 < 2; ++s2) {
                const int key = (ss * 2 + s2) * 16 + c;
                #pragma unroll
                for (int hh = 0; hh < 2; ++hh)
                    kb[s2][hh] = *(const bf16x8*)&ksh[key * 64 + (((hh * 4 + quad) ^ (c & 7)) * 8)];
            }
            bf16x8 va[4];
            const int k8lo = ss * 4 + (quad >> 1);
            const int half = (quad & 1) * 4;
            #pragma unroll
            for (int df = 0; df < 4; ++df) {
                const int row = (df * 16 + c) * 64;
                bf16x4 lo = *(const bf16x4*)&vsh[row + ((k8lo       ^ (c & 7)) * 8) + half];
                bf16x4 hi = *(const bf16x4*)&vsh[row + (((k8lo + 2) ^ (c & 7)) * 8) + half];
                #pragma unroll
                for (int j = 0; j < 4; ++j) { va[df][j] = lo[j]; va[df][4 + j] = hi[j]; }
            }

            #pragma unroll
            for (int g = 0; g < 4; ++g) {
                f32x4 s0 = {}, s1 = {};
                s0 = MFMA32(kb[0][0], qf[g][0], s0);
                s0 = MFMA32(kb[0][1], qf[g][1], s0);
                s1 = MFMA32(kb[1][0], qf[g][0], s1);
                s1 = MFMA32(kb[1][1], qf[g][1], s1);

                bf16x8 pb;
                #pragma unroll
                for (int r = 0; r < 4; ++r) {
                    pb[r]     = (bf16_t)EXP2F(s0[r]);
                    pb[4 + r] = (bf16_t)EXP2F(s1[r]);
                }

                #pragma unroll
                for (int df = 0; df < 4; ++df)
                    O[g][df] = MFMA32(va[df], pb, O[g][df]);
                O5[g] = MFMA32(ones, pb, O5[g]);   // l accumulation
            }
        }
    }

    #pragma unroll
    for (int g = 0; g < 4; ++g) {
        const float inv_l = 1.0f / O5[g][0];       // full row-sum for q
        const int q = qb + g * 16 + c;
        #pragma unroll
        for (int df = 0; df < 4; ++df) {
            bf16x4 o;
            #pragma unroll
            for (int r = 0; r < 4; ++r) o[r] = (bf16_t)(O[g][df][r] * inv_l);
            *(bf16x4*)(ctx + ((size_t)b * N_ + q) * C_ + h * 64 + df * 16 + quad * 4) = o;
        }
    }
}

extern "C" void kernel_launch(void* const* d_in, const int* in_sizes, int n_in,
                              void* d_out, int out_size, void* d_ws, size_t ws_size,
                              hipStream_t stream) {
    const float* x  = (const float*)d_in[0];
    const float* Wq = (const float*)d_in[1];
    const float* bq = (const float*)d_in[2];
    const float* Wk = (const float*)d_in[3];
    const float* bk = (const float*)d_in[4];
    const float* Wv = (const float*)d_in[5];
    const float* bv = (const float*)d_in[6];
    const float* Wo = (const float*)d_in[7];
    const float* bo = (const float*)d_in[8];

    bf16_t* ws = (bf16_t*)d_ws;
    const size_t per = (size_t)B_ * N_ * C_;     // 8,388,608 elems
    bf16_t* xb  = ws;                            // reused as ctx after QKV
    bf16_t* ctx = ws;
    bf16_t* Qb  = ws + per;
    bf16_t* Kb  = ws + 2 * per;
    bf16_t* Vtb = ws + 3 * per;
    bf16_t* Wtqkv = ws + 4 * per;                // [3072][1024] concatenated
    bf16_t* Wtq = Wtqkv;
    bf16_t* Wtk = Wtqkv + (size_t)C_ * C_;
    bf16_t* Wtv = Wtqkv + 2 * (size_t)C_ * C_;
    bf16_t* Wto = Wtqkv + 3 * (size_t)C_ * C_;

    dim3 blk(256);

    xconv_kernel<<<dim3(per / 2048), blk, 0, stream>>>(x, xb);
    wtrans_kernel<<<dim3(16, 16, 4), blk, 0, stream>>>(Wq, Wk, Wv, Wo, Wtq, Wtk, Wtv, Wto);

    gemm_qkv_kernel<<<dim3(384), dim3(512), 0, stream>>>(xb, Wtqkv, bq, bk, bv, Qb, Kb, Vtb);

    attn_kernel<<<dim3(512), blk, 0, stream>>>(Qb, Kb, Vtb, ctx);

    gemm_out_kernel<<<dim3(8, 64), blk, 0, stream>>>(ctx, Wto, bo, (float*)d_out);
}

// Round 4
// 262.898 us; speedup vs baseline: 1.0799x; 1.0419x over previous
//
#include <hip/hip_runtime.h>
#include <hip/hip_bf16.h>

typedef __bf16 bf16_t;
typedef __bf16 bf16x4 __attribute__((ext_vector_type(4)));
typedef __bf16 bf16x8 __attribute__((ext_vector_type(8)));
typedef float f32x4 __attribute__((ext_vector_type(4)));
typedef unsigned int u32;

#define B_ 4
#define N_ 2048
#define C_ 1024
#define H_ 16
#define D_ 64

#define MFMA32(a, b, c) __builtin_amdgcn_mfma_f32_16x16x32_bf16((a), (b), (c), 0, 0, 0)

#if __has_builtin(__builtin_amdgcn_exp2f)
#define EXP2F(x) __builtin_amdgcn_exp2f(x)
#else
#define EXP2F(x) __expf((x) * 0.6931471805599453f)
#endif

// 0.125 (=1/sqrt(D)) * log2(e): folded into Q at projection time
#define QSCALE 0.18033688011112042f

// async global->LDS, 16B per lane; LDS dst is wave-uniform base + lane*16
__device__ __forceinline__ void async16(const bf16_t* g, bf16_t* l) {
    __builtin_amdgcn_global_load_lds(
        (const u32 __attribute__((address_space(1)))*)g,
        (u32 __attribute__((address_space(3)))*)l, 16, 0, 0);
}

#define SBAR()  asm volatile("s_barrier" ::: "memory")
#define VM6()   asm volatile("s_waitcnt vmcnt(6)" ::: "memory")
#define VM0()   asm volatile("s_waitcnt vmcnt(0)" ::: "memory")

// ---------------------------------------------------------------------------
// x: f32 -> bf16 elementwise, 8 elems/thread
// ---------------------------------------------------------------------------
__global__ __launch_bounds__(256)
void xconv_kernel(const float* __restrict__ x, bf16_t* __restrict__ xb)
{
    const size_t i = ((size_t)blockIdx.x * 256 + threadIdx.x) * 8;
    float4 a = *(const float4*)(x + i);
    float4 b = *(const float4*)(x + i + 4);
    bf16x8 o;
    o[0] = (bf16_t)a.x; o[1] = (bf16_t)a.y; o[2] = (bf16_t)a.z; o[3] = (bf16_t)a.w;
    o[4] = (bf16_t)b.x; o[5] = (bf16_t)b.y; o[6] = (bf16_t)b.z; o[7] = (bf16_t)b.w;
    *(bf16x8*)(xb + i) = o;
}

// ---------------------------------------------------------------------------
// W[K][N] f32 -> Wt[N][K] bf16 (64x64 LDS tile transpose; z picks weight)
// ---------------------------------------------------------------------------
__global__ __launch_bounds__(256)
void wtrans_kernel(const float* __restrict__ W0, const float* __restrict__ W1,
                   const float* __restrict__ W2, const float* __restrict__ W3,
                   bf16_t* __restrict__ T0, bf16_t* __restrict__ T1,
                   bf16_t* __restrict__ T2, bf16_t* __restrict__ T3)
{
    const float* W; bf16_t* T;
    switch (blockIdx.z) {
        case 0:  W = W0; T = T0; break;
        case 1:  W = W1; T = T1; break;
        case 2:  W = W2; T = T2; break;
        default: W = W3; T = T3; break;
    }
    __shared__ bf16_t tile[64 * 72];
    const int tid = threadIdx.x;
    const int r0 = blockIdx.y * 64;          // k block
    const int c0 = blockIdx.x * 64;          // n block

    const int rr = tid >> 4;
    const int cc = (tid & 15) * 4;
    #pragma unroll
    for (int i = 0; i < 4; ++i) {
        const int row = rr + i * 16;
        float4 v = *(const float4*)(W + (size_t)(r0 + row) * C_ + c0 + cc);
        tile[(cc + 0) * 72 + row] = (bf16_t)v.x;
        tile[(cc + 1) * 72 + row] = (bf16_t)v.y;
        tile[(cc + 2) * 72 + row] = (bf16_t)v.z;
        tile[(cc + 3) * 72 + row] = (bf16_t)v.w;
    }
    __syncthreads();
    #pragma unroll
    for (int i = 0; i < 2; ++i) {
        const int ch = i * 256 + tid;
        const int n  = ch >> 3;
        const int k8 = (ch & 7) * 8;
        bf16x8 o = *(const bf16x8*)&tile[n * 72 + k8];
        *(bf16x8*)(T + (size_t)(c0 + n) * C_ + r0 + k8) = o;
    }
}

// ---------------------------------------------------------------------------
// Shared GEMM core: 128(M) x 256(N) tile, BK=64, 8 waves (2M x 4N),
// per-wave 64x64 -> acc[4][4] (64 f32/thread; total reg demand ~115 --
// fits even a 128-reg budget, spill IMPOSSIBLE; rounds 1-3's 256x256
// acc[8][4]=128 spilled ~47MB scratch-writes at every allocator setting).
// LDS 144KB TRIPLE-buffered: Abuf[3][ks:2][128*32] + Bbuf[3][ks:2][256*32].
// 6 global_load_lds per tile issued TWO tiles ahead; vmcnt(6) at tile end
// (t+1's slabs landed, t+2's stay in flight) -- never drains in steady
// state. 2 phases/tile (16 MFMA each) with raw-barrier pairs + setprio.
// Pre-swizzled global source: LDS (row, chunk sc) holds k-chunk sc^(row&3)
// -> conflict-free ds_read_b128 (read chunk quad at LDS chunk quad^(c&3)).
// ---------------------------------------------------------------------------
__device__ __forceinline__ void gemm128x256(const bf16_t* __restrict__ A,
                                            const bf16_t* __restrict__ Bt,
                                            bf16_t* smem, int m0, int n0,
                                            f32x4 (&acc)[4][4])
{
    const int tid  = threadIdx.x;            // 0..511
    const int w    = tid >> 6;               // 0..7
    const int lane = tid & 63;
    const int c    = lane & 15;
    const int quad = lane >> 4;
    const int wr   = w >> 2;                 // 0..1 (M)
    const int wc   = w & 3;                  // 0..3 (N)

    // staging: thread -> (row tid>>2, chunk tid&3); source k-chunk
    // pre-swizzled kc = (tid&3) ^ (row&3); rows 128 apart share kc.
    const int r0s = tid >> 2;                // 0..127
    const int kc  = (tid & 3) ^ (r0s & 3);
    const bf16_t* Ast0 = A  + (size_t)(m0 + r0s) * C_ + kc * 8;
    const bf16_t* Bst0 = Bt + (size_t)(n0 + r0s) * C_ + kc * 8;
    const bf16_t* Bst1 = Bt + (size_t)(n0 + r0s + 128) * C_ + kc * 8;

    const int xorc = (quad ^ (c & 3)) * 8;
    const bf16_t* Ard = smem + (wr * 64 + c) * 32 + xorc;
    const bf16_t* Brd = smem + 24576 + (wc * 64 + c) * 32 + xorc;
    bf16_t* sw = smem + w * 512;             // wave-uniform staging base

    bf16x8 af[4], bfv[4];

// A slab(buf,ks) = smem[buf*8192 + ks*4096 + row*32 + chunk*8]   (128 rows)
// B slab(buf,ks) = smem[24576 + buf*16384 + ks*8192 + row*32 + chunk*8] (256)
#define STAGE6(BUF, KOFF) do { \
    async16(Ast0 + (KOFF),      sw + (BUF) * 8192); \
    async16(Ast0 + (KOFF) + 32, sw + (BUF) * 8192 + 4096); \
    async16(Bst0 + (KOFF),      sw + 24576 + (BUF) * 16384); \
    async16(Bst1 + (KOFF),      sw + 24576 + (BUF) * 16384 + 4096); \
    async16(Bst0 + (KOFF) + 32, sw + 24576 + (BUF) * 16384 + 8192); \
    async16(Bst1 + (KOFF) + 32, sw + 24576 + (BUF) * 16384 + 12288); } while (0)

#define LDFRAGS(BUF, KS) do { \
    af[0]  = *(const bf16x8*)(Ard + (BUF) * 8192 + (KS) * 4096); \
    af[1]  = *(const bf16x8*)(Ard + (BUF) * 8192 + (KS) * 4096 + 512); \
    af[2]  = *(const bf16x8*)(Ard + (BUF) * 8192 + (KS) * 4096 + 1024); \
    af[3]  = *(const bf16x8*)(Ard + (BUF) * 8192 + (KS) * 4096 + 1536); \
    bfv[0] = *(const bf16x8*)(Brd + (BUF) * 16384 + (KS) * 8192); \
    bfv[1] = *(const bf16x8*)(Brd + (BUF) * 16384 + (KS) * 8192 + 512); \
    bfv[2] = *(const bf16x8*)(Brd + (BUF) * 16384 + (KS) * 8192 + 1024); \
    bfv[3] = *(const bf16x8*)(Brd + (BUF) * 16384 + (KS) * 8192 + 1536); } while (0)

#define MFMA16() do { \
    _Pragma("unroll") \
    for (int i = 0; i < 4; ++i) \
        _Pragma("unroll") \
        for (int j = 0; j < 4; ++j) \
            acc[i][j] = MFMA32(af[i], bfv[j], acc[i][j]); } while (0)

// tile on BUF; stages tile t+2 into NXT=(BUF+2)%3; VMK = vmcnt discipline.
#define TILE(BUF, NXT, DOSTAGE, KOFF, VMK) do { \
    if (DOSTAGE) STAGE6(NXT, KOFF); \
    LDFRAGS(BUF, 0); \
    SBAR(); \
    __builtin_amdgcn_s_setprio(1); MFMA16(); __builtin_amdgcn_s_setprio(0); \
    SBAR(); \
    LDFRAGS(BUF, 1); \
    SBAR(); \
    __builtin_amdgcn_s_setprio(1); MFMA16(); __builtin_amdgcn_s_setprio(0); \
    VMK; \
    SBAR(); \
} while (0)

    // prologue: tiles 0,1 staged (12 loads in flight); wait oldest 6 (tile 0)
    STAGE6(0, 0);
    STAGE6(1, 64);
    VM6();
    SBAR();

    #pragma unroll 1
    for (int tt = 0; tt < 4; ++tt) {         // tiles 0..11
        TILE(0, 2, 1, 128, VM6());
        TILE(1, 0, 1, 192, VM6());
        TILE(2, 1, 1, 256, VM6());
        Ast0 += 192; Bst0 += 192; Bst1 += 192;
    }
    TILE(0, 2, 1, 128, VM6());               // t=12 stages t=14
    TILE(1, 0, 1, 192, VM6());               // t=13 stages t=15
    TILE(2, 1, 0, 0,   VM0());               // t=14, drain t=15's loads
    TILE(0, 0, 0, 0,   ((void)0));           // t=15

#undef TILE
#undef MFMA16
#undef LDFRAGS
#undef STAGE6
}

// Fused QKV GEMM: A[8192,1024] @ Wqkv_t[3072,1024]^T + bias.
// Grid 768 = 3 exact CU-rounds. XCD map: XCD x owns m-blocks [8x,8x+8)
// (8*128 rows = 2MB A, L2-resident, reused 12x) x all 12 n-blocks.
// Epilogue: which = n0>>10: 0 -> Qb [B,H,N,D] PRE-SCALED by QSCALE,
// 1 -> Kb [B,H,N,D], 2 -> Vtb [B,H,D,N] (packed 8B stores).
__global__ __launch_bounds__(512)
void gemm_qkv_kernel(const bf16_t* __restrict__ A, const bf16_t* __restrict__ Wt,
                     const float* __restrict__ bq, const float* __restrict__ bk,
                     const float* __restrict__ bv,
                     bf16_t* __restrict__ Qb, bf16_t* __restrict__ Kb,
                     bf16_t* __restrict__ Vtb)
{
    __shared__ bf16_t smem[73728];           // 144 KiB

    const int bid = blockIdx.x;
    const int x8  = bid & 7;
    const int ii  = bid >> 3;                // 0..95
    const int mb  = x8 * 8 + (ii & 7);       // 0..63
    const int nb  = ii >> 3;                 // 0..11
    const int m0  = mb * 128, n0 = nb * 256;

    f32x4 acc[4][4] = {};
    gemm128x256(A, Wt, smem, m0, n0, acc);

    const int tid  = threadIdx.x;
    const int w    = tid >> 6;
    const int lane = tid & 63;
    const int c    = lane & 15;
    const int quad = lane >> 4;
    const int wr   = w >> 2;
    const int wc   = w & 3;

    const int which = n0 >> 10;              // 0 Q, 1 K, 2 V (tile-uniform)
    const float* bias = (which == 0) ? bq : (which == 1) ? bk : bv;

    #pragma unroll
    for (int nf = 0; nf < 4; ++nf) {
        const int col  = n0 + wc * 64 + nf * 16 + c;
        const int ncol = col & 1023;
        const float bsf = bias[ncol];
        const int h = ncol >> 6, d = ncol & 63;
        #pragma unroll
        for (int mf = 0; mf < 4; ++mf) {
            const int rbase = m0 + wr * 64 + mf * 16 + quad * 4;
            if (which < 2) {
                bf16_t* out = which ? Kb : Qb;
                const float sc = which ? 1.0f : QSCALE;
                #pragma unroll
                for (int r = 0; r < 4; ++r) {
                    const int row = rbase + r;
                    const int bb = row >> 11, n = row & 2047;
                    out[(((size_t)bb * H_ + h) * N_ + n) * D_ + d] =
                        (bf16_t)((acc[mf][nf][r] + bsf) * sc);
                }
            } else {
                const int bb = rbase >> 11, nbv = rbase & 2047;
                bf16x4 o;
                #pragma unroll
                for (int r = 0; r < 4; ++r) o[r] = (bf16_t)(acc[mf][nf][r] + bsf);
                *(bf16x4*)(Vtb + (((size_t)bb * H_ + h) * D_ + d) * N_ + nbv) = o;
            }
        }
    }
}

// Output GEMM: ctx[8192,1024]bf16 @ Wo_t[1024,1024]^T + bo -> f32.
// Same 128x256 core; grid 256 = exactly 1 CU-round.
__global__ __launch_bounds__(512)
void gemm_out_kernel(const bf16_t* __restrict__ A, const bf16_t* __restrict__ Bt,
                     const float* __restrict__ bias, float* __restrict__ out)
{
    __shared__ bf16_t smem[73728];           // 144 KiB

    const int bid = blockIdx.x;
    const int x8  = bid & 7;
    const int ii  = bid >> 3;                // 0..31
    const int mb  = x8 * 8 + (ii & 7);       // 0..63
    const int nb  = ii >> 3;                 // 0..3
    const int m0  = mb * 128, n0 = nb * 256;

    f32x4 acc[4][4] = {};
    gemm128x256(A, Bt, smem, m0, n0, acc);

    const int tid  = threadIdx.x;
    const int w    = tid >> 6;
    const int lane = tid & 63;
    const int c    = lane & 15;
    const int quad = lane >> 4;
    const int wr   = w >> 2;
    const int wc   = w & 3;

    #pragma unroll
    for (int nf = 0; nf < 4; ++nf) {
        const int col   = n0 + wc * 64 + nf * 16 + c;
        const float bsf = bias[col];
        #pragma unroll
        for (int mf = 0; mf < 4; ++mf) {
            const int rbase = m0 + wr * 64 + mf * 16 + quad * 4;
            #pragma unroll
            for (int r = 0; r < 4; ++r)
                out[(size_t)(rbase + r) * C_ + col] = acc[mf][nf][r] + bsf;
        }
    }
}

// ---------------------------------------------------------------------------
// Attention, S^T formulation, no-rescale streaming softmax, prescaled Q.
// Block = 4 waves, 256 q (wave: 64 q = 4 groups of 16 sharing K/V frags).
// Key tiles of 64 staged in LDS (XOR-swizzled 16B chunks).
// Grid 512; bh = (bid&7)*8 + ((bid>>3)&7), qtile = bid>>6 (XCD L2 reuse).
// ---------------------------------------------------------------------------
__global__ __launch_bounds__(256, 2)
void attn_kernel(const bf16_t* __restrict__ Q, const bf16_t* __restrict__ K,
                 const bf16_t* __restrict__ Vt, bf16_t* __restrict__ ctx)
{
    __shared__ bf16_t ksh[64 * 64];
    __shared__ bf16_t vsh[64 * 64];

    const int tid  = threadIdx.x;
    const int w    = tid >> 6;
    const int lane = tid & 63;
    const int c    = lane & 15;
    const int quad = lane >> 4;

    const int bid   = blockIdx.x;
    const int bh    = (bid & 7) * 8 + ((bid >> 3) & 7);   // 0..63
    const int qtile = bid >> 6;                           // 0..7
    const int b = bh >> 4, h = bh & 15;
    const size_t base = (size_t)bh * N_ * D_;
    const int qb = qtile * 256 + w * 64;                  // wave's 64 q-rows

    bf16x8 qf[4][2];
    #pragma unroll
    for (int g = 0; g < 4; ++g)
        #pragma unroll
        for (int hh = 0; hh < 2; ++hh)
            qf[g][hh] = *(const bf16x8*)(Q + base + (size_t)(qb + g * 16 + c) * D_ + hh * 32 + quad * 8);

    bf16x8 ones;
    #pragma unroll
    for (int j = 0; j < 8; ++j) ones[j] = (bf16_t)1.0f;

    f32x4 O[4][4] = {};
    f32x4 O5[4] = {};                               // row-sum accumulators

    for (int kt = 0; kt < N_; kt += 64) {
        __syncthreads();
        #pragma unroll
        for (int ph = 0; ph < 2; ++ph) {
            const int ch = ph * 256 + tid;       // 0..511
            const int rr = ch >> 3;              // key (K) / d (V)
            const int e8 = ch & 7;
            const int sw = (e8 ^ (rr & 7)) * 8;
            bf16x8 kv = *(const bf16x8*)(K  + base + (size_t)(kt + rr) * D_ + e8 * 8);
            *(bf16x8*)&ksh[rr * 64 + sw] = kv;
            bf16x8 vv = *(const bf16x8*)(Vt + base + (size_t)rr * N_ + kt + e8 * 8);
            *(bf16x8*)&vsh[rr * 64 + sw] = vv;
        }
        __syncthreads();

        #pragma unroll
        for (int ss = 0; ss < 2; ++ss) {         // two 32-key sub-steps
            bf16x8 kb[2][2];
            #pragma unroll
            for (int s2 = 0; s2 < 2; ++s2) {
                const int key = (ss * 2 + s2) * 16 + c;
                #pragma unroll
                for (int hh = 0; hh < 2; ++hh)
                    kb[s2][hh] = *(const bf16x8*)&ksh[key * 64 + (((hh * 4 + quad) ^ (c & 7)) * 8)];
            }
            bf16x8 va[4];
            const int k8lo = ss * 4 + (quad >> 1);
            const int half = (quad & 1) * 4;
            #pragma unroll
            for (int df = 0; df < 4; ++df) {
                const int row = (df * 16 + c) * 64;
                bf16x4 lo = *(const bf16x4*)&vsh[row + ((k8lo       ^ (c & 7)) * 8) + half];
                bf16x4 hi = *(const bf16x4*)&vsh[row + (((k8lo + 2) ^ (c & 7)) * 8) + half];
                #pragma unroll
                for (int j = 0; j < 4; ++j) { va[df][j] = lo[j]; va[df][4 + j] = hi[j]; }
            }

            #pragma unroll
            for (int g = 0; g < 4; ++g) {
                f32x4 s0 = {}, s1 = {};
                s0 = MFMA32(kb[0][0], qf[g][0], s0);
                s0 = MFMA32(kb[0][1], qf[g][1], s0);
                s1 = MFMA32(kb[1][0], qf[g][0], s1);
                s1 = MFMA32(kb[1][1], qf[g][1], s1);

                bf16x8 pb;
                #pragma unroll
                for (int r = 0; r < 4; ++r) {
                    pb[r]     = (bf16_t)EXP2F(s0[r]);
                    pb[4 + r] = (bf16_t)EXP2F(s1[r]);
                }

                #pragma unroll
                for (int df = 0; df < 4; ++df)
                    O[g][df] = MFMA32(va[df], pb, O[g][df]);
                O5[g] = MFMA32(ones, pb, O5[g]);   // l accumulation
            }
        }
    }

    #pragma unroll
    for (int g = 0; g < 4; ++g) {
        const float inv_l = 1.0f / O5[g][0];       // full row-sum for q
        const int q = qb + g * 16 + c;
        #pragma unroll
        for (int df = 0; df < 4; ++df) {
            bf16x4 o;
            #pragma unroll
            for (int r = 0; r < 4; ++r) o[r] = (bf16_t)(O[g][df][r] * inv_l);
            *(bf16x4*)(ctx + ((size_t)b * N_ + q) * C_ + h * 64 + df * 16 + quad * 4) = o;
        }
    }
}

extern "C" void kernel_launch(void* const* d_in, const int* in_sizes, int n_in,
                              void* d_out, int out_size, void* d_ws, size_t ws_size,
                              hipStream_t stream) {
    const float* x  = (const float*)d_in[0];
    const float* Wq = (const float*)d_in[1];
    const float* bq = (const float*)d_in[2];
    const float* Wk = (const float*)d_in[3];
    const float* bk = (const float*)d_in[4];
    const float* Wv = (const float*)d_in[5];
    const float* bv = (const float*)d_in[6];
    const float* Wo = (const float*)d_in[7];
    const float* bo = (const float*)d_in[8];

    bf16_t* ws = (bf16_t*)d_ws;
    const size_t per = (size_t)B_ * N_ * C_;     // 8,388,608 elems
    bf16_t* xb  = ws;                            // reused as ctx after QKV
    bf16_t* ctx = ws;
    bf16_t* Qb  = ws + per;
    bf16_t* Kb  = ws + 2 * per;
    bf16_t* Vtb = ws + 3 * per;
    bf16_t* Wtqkv = ws + 4 * per;                // [3072][1024] concatenated
    bf16_t* Wtq = Wtqkv;
    bf16_t* Wtk = Wtqkv + (size_t)C_ * C_;
    bf16_t* Wtv = Wtqkv + 2 * (size_t)C_ * C_;
    bf16_t* Wto = Wtqkv + 3 * (size_t)C_ * C_;

    dim3 blk(256);

    xconv_kernel<<<dim3(per / 2048), blk, 0, stream>>>(x, xb);
    wtrans_kernel<<<dim3(16, 16, 4), blk, 0, stream>>>(Wq, Wk, Wv, Wo, Wtq, Wtk, Wtv, Wto);

    gemm_qkv_kernel<<<dim3(768), dim3(512), 0, stream>>>(xb, Wtqkv, bq, bk, bv, Qb, Kb, Vtb);

    attn_kernel<<<dim3(512), blk, 0, stream>>>(Qb, Kb, Vtb, ctx);

    gemm_out_kernel<<<dim3(256), dim3(512), 0, stream>>>(ctx, Wto, bo, (float*)d_out);
}

// Round 5
// 252.118 us; speedup vs baseline: 1.1261x; 1.0428x over previous
//
#include <hip/hip_runtime.h>
#include <hip/hip_bf16.h>

typedef __bf16 bf16_t;
typedef __bf16 bf16x4 __attribute__((ext_vector_type(4)));
typedef __bf16 bf16x8 __attribute__((ext_vector_type(8)));
typedef float f32x4 __attribute__((ext_vector_type(4)));
typedef unsigned int u32;

#define B_ 4
#define N_ 2048
#define C_ 1024
#define H_ 16
#define D_ 64

#define MFMA32(a, b, c) __builtin_amdgcn_mfma_f32_16x16x32_bf16((a), (b), (c), 0, 0, 0)

#if __has_builtin(__builtin_amdgcn_exp2f)
#define EXP2F(x) __builtin_amdgcn_exp2f(x)
#else
#define EXP2F(x) __expf((x) * 0.6931471805599453f)
#endif

// 0.125 (=1/sqrt(D)) * log2(e): folded into Q at projection time
#define QSCALE 0.18033688011112042f

// async global->LDS, 16B per lane; LDS dst is wave-uniform base + lane*16
__device__ __forceinline__ void async16(const bf16_t* g, bf16_t* l) {
    __builtin_amdgcn_global_load_lds(
        (const u32 __attribute__((address_space(1)))*)g,
        (u32 __attribute__((address_space(3)))*)l, 16, 0, 0);
}

#define SBAR()  asm volatile("s_barrier" ::: "memory")
#define VM6()   asm volatile("s_waitcnt vmcnt(6)" ::: "memory")
#define VM0()   asm volatile("s_waitcnt vmcnt(0)" ::: "memory")

// ---------------------------------------------------------------------------
// x: f32 -> bf16 elementwise, 8 elems/thread
// ---------------------------------------------------------------------------
__global__ __launch_bounds__(256)
void xconv_kernel(const float* __restrict__ x, bf16_t* __restrict__ xb)
{
    const size_t i = ((size_t)blockIdx.x * 256 + threadIdx.x) * 8;
    float4 a = *(const float4*)(x + i);
    float4 b = *(const float4*)(x + i + 4);
    bf16x8 o;
    o[0] = (bf16_t)a.x; o[1] = (bf16_t)a.y; o[2] = (bf16_t)a.z; o[3] = (bf16_t)a.w;
    o[4] = (bf16_t)b.x; o[5] = (bf16_t)b.y; o[6] = (bf16_t)b.z; o[7] = (bf16_t)b.w;
    *(bf16x8*)(xb + i) = o;
}

// ---------------------------------------------------------------------------
// W[K][N] f32 -> Wt[N][K] bf16 (64x64 LDS tile transpose; z picks weight)
// ---------------------------------------------------------------------------
__global__ __launch_bounds__(256)
void wtrans_kernel(const float* __restrict__ W0, const float* __restrict__ W1,
                   const float* __restrict__ W2, const float* __restrict__ W3,
                   bf16_t* __restrict__ T0, bf16_t* __restrict__ T1,
                   bf16_t* __restrict__ T2, bf16_t* __restrict__ T3)
{
    const float* W; bf16_t* T;
    switch (blockIdx.z) {
        case 0:  W = W0; T = T0; break;
        case 1:  W = W1; T = T1; break;
        case 2:  W = W2; T = T2; break;
        default: W = W3; T = T3; break;
    }
    __shared__ bf16_t tile[64 * 72];
    const int tid = threadIdx.x;
    const int r0 = blockIdx.y * 64;          // k block
    const int c0 = blockIdx.x * 64;          // n block

    const int rr = tid >> 4;
    const int cc = (tid & 15) * 4;
    #pragma unroll
    for (int i = 0; i < 4; ++i) {
        const int row = rr + i * 16;
        float4 v = *(const float4*)(W + (size_t)(r0 + row) * C_ + c0 + cc);
        tile[(cc + 0) * 72 + row] = (bf16_t)v.x;
        tile[(cc + 1) * 72 + row] = (bf16_t)v.y;
        tile[(cc + 2) * 72 + row] = (bf16_t)v.z;
        tile[(cc + 3) * 72 + row] = (bf16_t)v.w;
    }
    __syncthreads();
    #pragma unroll
    for (int i = 0; i < 2; ++i) {
        const int ch = i * 256 + tid;
        const int n  = ch >> 3;
        const int k8 = (ch & 7) * 8;
        bf16x8 o = *(const bf16x8*)&tile[n * 72 + k8];
        *(bf16x8*)(T + (size_t)(c0 + n) * C_ + r0 + k8) = o;
    }
}

// ---------------------------------------------------------------------------
// Shared GEMM core: 128(M) x 256(N) tile, BK=64, 8 waves (2M x 4N),
// per-wave 64x64 -> acc[4][4] (64 f32, AGPR-eligible; arch-VGPR demand
// ~90 incl. 16 bf16x8 frags -- under the observed ~112 allocator cap).
// LDS 144KB TRIPLE-buffered; 6 global_load_lds per tile issued TWO tiles
// ahead; vmcnt(6) at tile end -- never drains in steady state.
// ROUND-5 CHANGES (from counter evidence):
// (1) Bank-conflict fix: XOR term is (row>>1)&3, NOT row&3. With row
//     stride 64B, slot = (row&1, chunk); old XOR collided lanes c and c+4
//     in every 8-lane issue group (6.29M conflict cycles = 2x LDS drain).
//     New mapping gives all 8 slots distinct per 8 consecutive lanes.
// (2) ONE phase + ONE barrier per K-tile: {stage; 16 ds_read; 32 MFMA;
//     vmcnt(6); s_barrier}. The old head-barrier was scheduling-only:
//     correctness is carried entirely by VM-before-SBAR at tile end
//     (staging into buf(t+2)=buf(t-1) is gated by t-1's trailing barrier;
//     cross-wave staging visibility by VM6 preceding SBAR). Waves now
//     de-lockstep within a tile -> LDS drain hides under MFMA.
// ---------------------------------------------------------------------------
__device__ __forceinline__ void gemm128x256(const bf16_t* __restrict__ A,
                                            const bf16_t* __restrict__ Bt,
                                            bf16_t* smem, int m0, int n0,
                                            f32x4 (&acc)[4][4])
{
    const int tid  = threadIdx.x;            // 0..511
    const int w    = tid >> 6;               // 0..7
    const int lane = tid & 63;
    const int c    = lane & 15;
    const int quad = lane >> 4;
    const int wr   = w >> 2;                 // 0..1 (M)
    const int wc   = w & 3;                  // 0..3 (N)

    // staging: thread -> (row tid>>2, chunk tid&3); source k-chunk
    // pre-swizzled kc = (tid&3) ^ ((row>>1)&3); rows 128 apart share kc.
    const int r0s = tid >> 2;                // 0..127
    const int kc  = (tid & 3) ^ ((r0s >> 1) & 3);
    const bf16_t* Ast0 = A  + (size_t)(m0 + r0s) * C_ + kc * 8;
    const bf16_t* Bst0 = Bt + (size_t)(n0 + r0s) * C_ + kc * 8;
    const bf16_t* Bst1 = Bt + (size_t)(n0 + r0s + 128) * C_ + kc * 8;

    // read base: fragment rows are (16*i + c); base row offsets are
    // multiples of 16, so (row>>1)&3 == (c>>1)&3 -- row-block-invariant.
    const int xorc = (quad ^ ((c >> 1) & 3)) * 8;
    const bf16_t* Ard = smem + (wr * 64 + c) * 32 + xorc;
    const bf16_t* Brd = smem + 24576 + (wc * 64 + c) * 32 + xorc;
    bf16_t* sw = smem + w * 512;             // wave-uniform staging base

    bf16x8 af[2][4], bfv[2][4];

// A slab(buf,ks) = smem[buf*8192 + ks*4096 + row*32 + chunk*8]   (128 rows)
// B slab(buf,ks) = smem[24576 + buf*16384 + ks*8192 + row*32 + chunk*8] (256)
#define STAGE6(BUF, KOFF) do { \
    async16(Ast0 + (KOFF),      sw + (BUF) * 8192); \
    async16(Ast0 + (KOFF) + 32, sw + (BUF) * 8192 + 4096); \
    async16(Bst0 + (KOFF),      sw + 24576 + (BUF) * 16384); \
    async16(Bst1 + (KOFF),      sw + 24576 + (BUF) * 16384 + 4096); \
    async16(Bst0 + (KOFF) + 32, sw + 24576 + (BUF) * 16384 + 8192); \
    async16(Bst1 + (KOFF) + 32, sw + 24576 + (BUF) * 16384 + 12288); } while (0)

#define LDFRAGS16(BUF) do { \
    _Pragma("unroll") \
    for (int ks = 0; ks < 2; ++ks) { \
        _Pragma("unroll") \
        for (int i = 0; i < 4; ++i) \
            af[ks][i]  = *(const bf16x8*)(Ard + (BUF) * 8192 + ks * 4096 + i * 512); \
        _Pragma("unroll") \
        for (int j = 0; j < 4; ++j) \
            bfv[ks][j] = *(const bf16x8*)(Brd + (BUF) * 16384 + ks * 8192 + j * 512); \
    } } while (0)

#define MFMA32ALL() do { \
    _Pragma("unroll") \
    for (int ks = 0; ks < 2; ++ks) \
        _Pragma("unroll") \
        for (int i = 0; i < 4; ++i) \
            _Pragma("unroll") \
            for (int j = 0; j < 4; ++j) \
                acc[i][j] = MFMA32(af[ks][i], bfv[ks][j], acc[i][j]); } while (0)

// tile on BUF; stages tile t+2 into NXT=(BUF+2)%3; VMK = vmcnt discipline.
// Single barrier per tile (see header comment).
#define TILE(BUF, NXT, DOSTAGE, KOFF, VMK) do { \
    if (DOSTAGE) STAGE6(NXT, KOFF); \
    LDFRAGS16(BUF); \
    __builtin_amdgcn_s_setprio(1); MFMA32ALL(); __builtin_amdgcn_s_setprio(0); \
    VMK; \
    SBAR(); \
} while (0)

    // prologue: tiles 0,1 staged (12 loads in flight); wait oldest 6 (tile 0)
    STAGE6(0, 0);
    STAGE6(1, 64);
    VM6();
    SBAR();

    #pragma unroll 1
    for (int tt = 0; tt < 4; ++tt) {         // tiles 0..11
        TILE(0, 2, 1, 128, VM6());
        TILE(1, 0, 1, 192, VM6());
        TILE(2, 1, 1, 256, VM6());
        Ast0 += 192; Bst0 += 192; Bst1 += 192;
    }
    TILE(0, 2, 1, 128, VM6());               // t=12 stages t=14
    TILE(1, 0, 1, 192, VM6());               // t=13 stages t=15
    TILE(2, 1, 0, 0,   VM0());               // t=14, drain t=15's loads
    TILE(0, 0, 0, 0,   ((void)0));           // t=15

#undef TILE
#undef MFMA32ALL
#undef LDFRAGS16
#undef STAGE6
}

// Fused QKV GEMM: A[8192,1024] @ Wqkv_t[3072,1024]^T + bias.
// Grid 768 = 3 exact CU-rounds. XCD map: XCD x owns m-blocks [8x,8x+8)
// (8*128 rows = 2MB A, L2-resident, reused 12x) x all 12 n-blocks.
// Epilogue: which = n0>>10: 0 -> Qb [B,H,N,D] PRE-SCALED by QSCALE,
// 1 -> Kb [B,H,N,D], 2 -> Vtb [B,H,D,N] (packed 8B stores).
__global__ __launch_bounds__(512)
void gemm_qkv_kernel(const bf16_t* __restrict__ A, const bf16_t* __restrict__ Wt,
                     const float* __restrict__ bq, const float* __restrict__ bk,
                     const float* __restrict__ bv,
                     bf16_t* __restrict__ Qb, bf16_t* __restrict__ Kb,
                     bf16_t* __restrict__ Vtb)
{
    __shared__ bf16_t smem[73728];           // 144 KiB

    const int bid = blockIdx.x;
    const int x8  = bid & 7;
    const int ii  = bid >> 3;                // 0..95
    const int mb  = x8 * 8 + (ii & 7);       // 0..63
    const int nb  = ii >> 3;                 // 0..11
    const int m0  = mb * 128, n0 = nb * 256;

    f32x4 acc[4][4] = {};
    gemm128x256(A, Wt, smem, m0, n0, acc);

    const int tid  = threadIdx.x;
    const int w    = tid >> 6;
    const int lane = tid & 63;
    const int c    = lane & 15;
    const int quad = lane >> 4;
    const int wr   = w >> 2;
    const int wc   = w & 3;

    const int which = n0 >> 10;              // 0 Q, 1 K, 2 V (tile-uniform)
    const float* bias = (which == 0) ? bq : (which == 1) ? bk : bv;

    #pragma unroll
    for (int nf = 0; nf < 4; ++nf) {
        const int col  = n0 + wc * 64 + nf * 16 + c;
        const int ncol = col & 1023;
        const float bsf = bias[ncol];
        const int h = ncol >> 6, d = ncol & 63;
        #pragma unroll
        for (int mf = 0; mf < 4; ++mf) {
            const int rbase = m0 + wr * 64 + mf * 16 + quad * 4;
            if (which < 2) {
                bf16_t* out = which ? Kb : Qb;
                const float sc = which ? 1.0f : QSCALE;
                #pragma unroll
                for (int r = 0; r < 4; ++r) {
                    const int row = rbase + r;
                    const int bb = row >> 11, n = row & 2047;
                    out[(((size_t)bb * H_ + h) * N_ + n) * D_ + d] =
                        (bf16_t)((acc[mf][nf][r] + bsf) * sc);
                }
            } else {
                const int bb = rbase >> 11, nbv = rbase & 2047;
                bf16x4 o;
                #pragma unroll
                for (int r = 0; r < 4; ++r) o[r] = (bf16_t)(acc[mf][nf][r] + bsf);
                *(bf16x4*)(Vtb + (((size_t)bb * H_ + h) * D_ + d) * N_ + nbv) = o;
            }
        }
    }
}

// Output GEMM: ctx[8192,1024]bf16 @ Wo_t[1024,1024]^T + bo -> f32.
// Same 128x256 core; grid 256 = exactly 1 CU-round.
__global__ __launch_bounds__(512)
void gemm_out_kernel(const bf16_t* __restrict__ A, const bf16_t* __restrict__ Bt,
                     const float* __restrict__ bias, float* __restrict__ out)
{
    __shared__ bf16_t smem[73728];           // 144 KiB

    const int bid = blockIdx.x;
    const int x8  = bid & 7;
    const int ii  = bid >> 3;                // 0..31
    const int mb  = x8 * 8 + (ii & 7);       // 0..63
    const int nb  = ii >> 3;                 // 0..3
    const int m0  = mb * 128, n0 = nb * 256;

    f32x4 acc[4][4] = {};
    gemm128x256(A, Bt, smem, m0, n0, acc);

    const int tid  = threadIdx.x;
    const int w    = tid >> 6;
    const int lane = tid & 63;
    const int c    = lane & 15;
    const int quad = lane >> 4;
    const int wr   = w >> 2;
    const int wc   = w & 3;

    #pragma unroll
    for (int nf = 0; nf < 4; ++nf) {
        const int col   = n0 + wc * 64 + nf * 16 + c;
        const float bsf = bias[col];
        #pragma unroll
        for (int mf = 0; mf < 4; ++mf) {
            const int rbase = m0 + wr * 64 + mf * 16 + quad * 4;
            #pragma unroll
            for (int r = 0; r < 4; ++r)
                out[(size_t)(rbase + r) * C_ + col] = acc[mf][nf][r] + bsf;
        }
    }
}

// ---------------------------------------------------------------------------
// Attention, S^T formulation, no-rescale streaming softmax, prescaled Q.
// Block = 4 waves, 256 q (wave: 64 q = 4 groups of 16 sharing K/V frags).
// Key tiles of 64 staged in LDS (XOR-swizzled 16B chunks).
// Grid 512; bh = (bid&7)*8 + ((bid>>3)&7), qtile = bid>>6 (XCD L2 reuse).
// ---------------------------------------------------------------------------
__global__ __launch_bounds__(256, 2)
void attn_kernel(const bf16_t* __restrict__ Q, const bf16_t* __restrict__ K,
                 const bf16_t* __restrict__ Vt, bf16_t* __restrict__ ctx)
{
    __shared__ bf16_t ksh[64 * 64];
    __shared__ bf16_t vsh[64 * 64];

    const int tid  = threadIdx.x;
    const int w    = tid >> 6;
    const int lane = tid & 63;
    const int c    = lane & 15;
    const int quad = lane >> 4;

    const int bid   = blockIdx.x;
    const int bh    = (bid & 7) * 8 + ((bid >> 3) & 7);   // 0..63
    const int qtile = bid >> 6;                           // 0..7
    const int b = bh >> 4, h = bh & 15;
    const size_t base = (size_t)bh * N_ * D_;
    const int qb = qtile * 256 + w * 64;                  // wave's 64 q-rows

    bf16x8 qf[4][2];
    #pragma unroll
    for (int g = 0; g < 4; ++g)
        #pragma unroll
        for (int hh = 0; hh < 2; ++hh)
            qf[g][hh] = *(const bf16x8*)(Q + base + (size_t)(qb + g * 16 + c) * D_ + hh * 32 + quad * 8);

    bf16x8 ones;
    #pragma unroll
    for (int j = 0; j < 8; ++j) ones[j] = (bf16_t)1.0f;

    f32x4 O[4][4] = {};
    f32x4 O5[4] = {};                               // row-sum accumulators

    for (int kt = 0; kt < N_; kt += 64) {
        __syncthreads();
        #pragma unroll
        for (int ph = 0; ph < 2; ++ph) {
            const int ch = ph * 256 + tid;       // 0..511
            const int rr = ch >> 3;              // key (K) / d (V)
            const int e8 = ch & 7;
            const int sw = (e8 ^ (rr & 7)) * 8;
            bf16x8 kv = *(const bf16x8*)(K  + base + (size_t)(kt + rr) * D_ + e8 * 8);
            *(bf16x8*)&ksh[rr * 64 + sw] = kv;
            bf16x8 vv = *(const bf16x8*)(Vt + base + (size_t)rr * N_ + kt + e8 * 8);
            *(bf16x8*)&vsh[rr * 64 + sw] = vv;
        }
        __syncthreads();

        #pragma unroll
        for (int ss = 0; ss < 2; ++ss) {         // two 32-key sub-steps
            bf16x8 kb[2][2];
            #pragma unroll
            for (int s2 = 0; s2 < 2; ++s2) {
                const int key = (ss * 2 + s2) * 16 + c;
                #pragma unroll
                for (int hh = 0; hh < 2; ++hh)
                    kb[s2][hh] = *(const bf16x8*)&ksh[key * 64 + (((hh * 4 + quad) ^ (c & 7)) * 8)];
            }
            bf16x8 va[4];
            const int k8lo = ss * 4 + (quad >> 1);
            const int half = (quad & 1) * 4;
            #pragma unroll
            for (int df = 0; df < 4; ++df) {
                const int row = (df * 16 + c) * 64;
                bf16x4 lo = *(const bf16x4*)&vsh[row + ((k8lo       ^ (c & 7)) * 8) + half];
                bf16x4 hi = *(const bf16x4*)&vsh[row + (((k8lo + 2) ^ (c & 7)) * 8) + half];
                #pragma unroll
                for (int j = 0; j < 4; ++j) { va[df][j] = lo[j]; va[df][4 + j] = hi[j]; }
            }

            #pragma unroll
            for (int g = 0; g < 4; ++g) {
                f32x4 s0 = {}, s1 = {};
                s0 = MFMA32(kb[0][0], qf[g][0], s0);
                s0 = MFMA32(kb[0][1], qf[g][1], s0);
                s1 = MFMA32(kb[1][0], qf[g][0], s1);
                s1 = MFMA32(kb[1][1], qf[g][1], s1);

                bf16x8 pb;
                #pragma unroll
                for (int r = 0; r < 4; ++r) {
                    pb[r]     = (bf16_t)EXP2F(s0[r]);
                    pb[4 + r] = (bf16_t)EXP2F(s1[r]);
                }

                #pragma unroll
                for (int df = 0; df < 4; ++df)
                    O[g][df] = MFMA32(va[df], pb, O[g][df]);
                O5[g] = MFMA32(ones, pb, O5[g]);   // l accumulation
            }
        }
    }

    #pragma unroll
    for (int g = 0; g < 4; ++g) {
        const float inv_l = 1.0f / O5[g][0];       // full row-sum for q
        const int q = qb + g * 16 + c;
        #pragma unroll
        for (int df = 0; df < 4; ++df) {
            bf16x4 o;
            #pragma unroll
            for (int r = 0; r < 4; ++r) o[r] = (bf16_t)(O[g][df][r] * inv_l);
            *(bf16x4*)(ctx + ((size_t)b * N_ + q) * C_ + h * 64 + df * 16 + quad * 4) = o;
        }
    }
}

extern "C" void kernel_launch(void* const* d_in, const int* in_sizes, int n_in,
                              void* d_out, int out_size, void* d_ws, size_t ws_size,
                              hipStream_t stream) {
    const float* x  = (const float*)d_in[0];
    const float* Wq = (const float*)d_in[1];
    const float* bq = (const float*)d_in[2];
    const float* Wk = (const float*)d_in[3];
    const float* bk = (const float*)d_in[4];
    const float* Wv = (const float*)d_in[5];
    const float* bv = (const float*)d_in[6];
    const float* Wo = (const float*)d_in[7];
    const float* bo = (const float*)d_in[8];

    bf16_t* ws = (bf16_t*)d_ws;
    const size_t per = (size_t)B_ * N_ * C_;     // 8,388,608 elems
    bf16_t* xb  = ws;                            // reused as ctx after QKV
    bf16_t* ctx = ws;
    bf16_t* Qb  = ws + per;
    bf16_t* Kb  = ws + 2 * per;
    bf16_t* Vtb = ws + 3 * per;
    bf16_t* Wtqkv = ws + 4 * per;                // [3072][1024] concatenated
    bf16_t* Wtq = Wtqkv;
    bf16_t* Wtk = Wtqkv + (size_t)C_ * C_;
    bf16_t* Wtv = Wtqkv + 2 * (size_t)C_ * C_;
    bf16_t* Wto = Wtqkv + 3 * (size_t)C_ * C_;

    dim3 blk(256);

    xconv_kernel<<<dim3(per / 2048), blk, 0, stream>>>(x, xb);
    wtrans_kernel<<<dim3(16, 16, 4), blk, 0, stream>>>(Wq, Wk, Wv, Wo, Wtq, Wtk, Wtv, Wto);

    gemm_qkv_kernel<<<dim3(768), dim3(512), 0, stream>>>(xb, Wtqkv, bq, bk, bv, Qb, Kb, Vtb);

    attn_kernel<<<dim3(512), blk, 0, stream>>>(Qb, Kb, Vtb, ctx);

    gemm_out_kernel<<<dim3(256), dim3(512), 0, stream>>>(ctx, Wto, bo, (float*)d_out);
}